// Round 1
// baseline (143.954 us; speedup 1.0000x reference)
//
#include <hip/hip_runtime.h>

// LeakyIntegrator: T=64 step scan, independent per (c,h,w) element.
// m_t = r ? img : (a ? (1-lam)*m + lam*img*cov + lam*m*(1-cov) : m)
// c_t = r ? cov : (a ? clip(c+cov,0,1) : c)
// reset[0] forced true (map memory starts empty).

#define LAM 0.2f
#define T_STEPS 64
#define C_CH 64
#define H_DIM 128
#define W_DIM 128
#define HW (H_DIM * W_DIM)            // 16384
#define CHW (C_CH * HW)               // 1048576
#define MAPS_SIZE (T_STEPS * CHW)     // 67108864 floats

// Masks may arrive as int32 or as 1-byte bools. add_mask is all-True by
// construction, so its first 4 bytes disambiguate: 0x00000001 -> int32,
// 0x01010101 -> bytes.
__device__ __forceinline__ void load_masks(const void* add_p, const void* reset_p,
                                           unsigned long long& abits,
                                           unsigned long long& rbits) {
    const unsigned int w0 = *(const unsigned int*)add_p;
    abits = 0ull; rbits = 0ull;
    if (w0 == 1u) {  // int32 bools
        const int* a = (const int*)add_p;
        const int* r = (const int*)reset_p;
        #pragma unroll
        for (int t = 0; t < T_STEPS; ++t) {
            abits |= (unsigned long long)(a[t] != 0) << t;
            rbits |= (unsigned long long)(r[t] != 0) << t;
        }
    } else {         // byte bools
        const unsigned char* a = (const unsigned char*)add_p;
        const unsigned char* r = (const unsigned char*)reset_p;
        #pragma unroll
        for (int t = 0; t < T_STEPS; ++t) {
            abits |= (unsigned long long)(a[t] != 0) << t;
            rbits |= (unsigned long long)(r[t] != 0) << t;
        }
    }
    rbits |= 1ull;   // step 0 always resets
}

__global__ __launch_bounds__(256) void li_maps_kernel(
        const float* __restrict__ img, const float* __restrict__ cov,
        const void* __restrict__ addm, const void* __restrict__ resetm,
        float* __restrict__ out) {
    const int tid  = blockIdx.x * blockDim.x + threadIdx.x;  // 0 .. CHW/4-1
    const int pix4 = tid & (HW / 4 - 1);                     // 0..4095
    const int c    = tid >> 12;                              // 0..63
    const int base    = c * HW + pix4 * 4;                   // element offset in a t-slice
    const int covbase = pix4 * 4;

    unsigned long long abits, rbits;
    load_masks(addm, resetm, abits, rbits);

    float4 m = make_float4(0.f, 0.f, 0.f, 0.f);
    for (int t = 0; t < T_STEPS; ++t) {
        const float4 im = *(const float4*)(img + (size_t)t * CHW + base);
        const float4 cv = *(const float4*)(cov + (size_t)t * HW + covbase);
        const bool r = (rbits >> t) & 1ull;
        const bool a = (abits >> t) & 1ull;

        float4 mu;  // (1-lam)*m + lam*img*cov + lam*m*(1-cov), reference op order
        mu.x = (1.f - LAM) * m.x + (LAM * im.x) * cv.x + (LAM * m.x) * (1.f - cv.x);
        mu.y = (1.f - LAM) * m.y + (LAM * im.y) * cv.y + (LAM * m.y) * (1.f - cv.y);
        mu.z = (1.f - LAM) * m.z + (LAM * im.z) * cv.z + (LAM * m.z) * (1.f - cv.z);
        mu.w = (1.f - LAM) * m.w + (LAM * im.w) * cv.w + (LAM * m.w) * (1.f - cv.w);

        float4 mn;
        mn.x = r ? im.x : (a ? mu.x : m.x);
        mn.y = r ? im.y : (a ? mu.y : m.y);
        mn.z = r ? im.z : (a ? mu.z : m.z);
        mn.w = r ? im.w : (a ? mu.w : m.w);
        m = mn;

        *(float4*)(out + (size_t)t * CHW + base) = m;
    }
}

__global__ __launch_bounds__(256) void li_covs_kernel(
        const float* __restrict__ cov,
        const void* __restrict__ addm, const void* __restrict__ resetm,
        float* __restrict__ out) {
    const int tid  = blockIdx.x * blockDim.x + threadIdx.x;  // 0 .. HW/4-1
    const int base = tid * 4;

    unsigned long long abits, rbits;
    load_masks(addm, resetm, abits, rbits);

    float4 cc = make_float4(0.f, 0.f, 0.f, 0.f);
    for (int t = 0; t < T_STEPS; ++t) {
        const float4 cv = *(const float4*)(cov + (size_t)t * HW + base);
        const bool r = (rbits >> t) & 1ull;
        const bool a = (abits >> t) & 1ull;

        float4 cu;  // clip(c + cov, 0, 1)
        cu.x = fminf(fmaxf(cc.x + cv.x, 0.f), 1.f);
        cu.y = fminf(fmaxf(cc.y + cv.y, 0.f), 1.f);
        cu.z = fminf(fmaxf(cc.z + cv.z, 0.f), 1.f);
        cu.w = fminf(fmaxf(cc.w + cv.w, 0.f), 1.f);

        float4 cn;
        cn.x = r ? cv.x : (a ? cu.x : cc.x);
        cn.y = r ? cv.y : (a ? cu.y : cc.y);
        cn.z = r ? cv.z : (a ? cu.z : cc.z);
        cn.w = r ? cv.w : (a ? cu.w : cc.w);
        cc = cn;

        *(float4*)(out + (size_t)MAPS_SIZE + (size_t)t * HW + base) = cc;
    }
}

extern "C" void kernel_launch(void* const* d_in, const int* in_sizes, int n_in,
                              void* d_out, int out_size, void* d_ws, size_t ws_size,
                              hipStream_t stream) {
    const float* img    = (const float*)d_in[0];
    const float* cov    = (const float*)d_in[1];
    const void*  addm   = d_in[2];
    const void*  resetm = d_in[3];
    float* out = (float*)d_out;

    // maps: one thread per (c, h, w/4) column -> CHW/4 = 262144 threads
    li_maps_kernel<<<(CHW / 4) / 256, 256, 0, stream>>>(img, cov, addm, resetm, out);
    // covs: one thread per (h, w/4) column -> HW/4 = 4096 threads
    li_covs_kernel<<<(HW / 4) / 256, 256, 0, stream>>>(cov, addm, resetm, out);
}

// Round 2
// 109.155 us; speedup vs baseline: 1.3188x; 1.3188x over previous
//
#include <hip/hip_runtime.h>

// LeakyIntegrator: T=64 scan, independent per (c,h,w) element.
// m_t = r ? img : (a ? (1-lam)*m + lam*img*cov + lam*m*(1-cov) : m)
// c_t = r ? cov : (a ? clip(c+cov,0,1) : c),   reset[0] forced true.
//
// Single fused kernel: one thread per (c,h,w/4) column; blocks with c==0
// additionally carry the coverage recurrence. 2-deep prefetch, full unroll
// (compile-time buffer indices), nontemporal img loads / out stores.

#define LAM 0.2f
#define T_STEPS 64
#define C_CH 64
#define H_DIM 128
#define W_DIM 128
#define HW (H_DIM * W_DIM)            // 16384
#define CHW (C_CH * HW)               // 1048576
#define MAPS_SIZE ((size_t)T_STEPS * CHW)

typedef float f32x4 __attribute__((ext_vector_type(4)));

// T == wave width: lane t loads mask[t], ballot packs the 64 bools.
// add_mask is all-True by construction -> first 4 bytes disambiguate
// int32 bools (0x00000001) vs byte bools (0x01010101).
__device__ __forceinline__ void load_masks_ballot(const void* add_p, const void* reset_p,
                                                  unsigned long long& abits,
                                                  unsigned long long& rbits) {
    const int lane = threadIdx.x & 63;
    const unsigned int w0 = *(const unsigned int*)add_p;
    int av, rv;
    if (w0 == 1u) {  // int32 bools
        av = ((const int*)add_p)[lane];
        rv = ((const int*)reset_p)[lane];
    } else {         // byte bools
        av = ((const unsigned char*)add_p)[lane];
        rv = ((const unsigned char*)reset_p)[lane];
    }
    abits = __ballot(av != 0);
    rbits = __ballot(rv != 0) | 1ull;   // step 0 always resets
}

__global__ __launch_bounds__(256, 4) void li_fused_kernel(
        const float* __restrict__ img, const float* __restrict__ cov,
        const void* __restrict__ addm, const void* __restrict__ resetm,
        float* __restrict__ out) {
    const int tid  = blockIdx.x * 256 + threadIdx.x;   // 0 .. CHW/4-1
    const int pix4 = tid & (HW / 4 - 1);               // 0..4095
    const int c    = tid >> 12;                        // 0..63
    const int base    = c * HW + pix4 * 4;
    const int covbase = pix4 * 4;
    const bool do_cov = (c == 0);                      // blocks 0..15, block-uniform

    unsigned long long abits, rbits;
    load_masks_ballot(addm, resetm, abits, rbits);

    const float* ip  = img + base;
    const float* cp  = cov + covbase;
    float*       mop = out + base;
    float*       cop = out + MAPS_SIZE + covbase;

    // 2-deep prefetch buffers; all indices compile-time after full unroll.
    f32x4 imb[2], cvb[2];
    imb[0] = __builtin_nontemporal_load((const f32x4*)(ip));
    cvb[0] = *(const f32x4*)(cp);
    imb[1] = __builtin_nontemporal_load((const f32x4*)(ip + CHW));
    cvb[1] = *(const f32x4*)(cp + HW);

    f32x4 m  = (f32x4)(0.f);
    f32x4 cc = (f32x4)(0.f);

    #pragma unroll
    for (int t = 0; t < T_STEPS; ++t) {
        const f32x4 im = imb[t & 1];
        const f32x4 cv = cvb[t & 1];
        if (t + 2 < T_STEPS) {
            imb[t & 1] = __builtin_nontemporal_load((const f32x4*)(ip + (size_t)(t + 2) * CHW));
            cvb[t & 1] = *(const f32x4*)(cp + (size_t)(t + 2) * HW);
        }
        const bool r = (rbits >> t) & 1ull;
        const bool a = (abits >> t) & 1ull;

        // reference op order: (1-lam)*m + (lam*img)*cov + (lam*m)*(1-cov)
        f32x4 mu;
        mu.x = (1.f - LAM) * m.x + (LAM * im.x) * cv.x + (LAM * m.x) * (1.f - cv.x);
        mu.y = (1.f - LAM) * m.y + (LAM * im.y) * cv.y + (LAM * m.y) * (1.f - cv.y);
        mu.z = (1.f - LAM) * m.z + (LAM * im.z) * cv.z + (LAM * m.z) * (1.f - cv.z);
        mu.w = (1.f - LAM) * m.w + (LAM * im.w) * cv.w + (LAM * m.w) * (1.f - cv.w);

        m.x = r ? im.x : (a ? mu.x : m.x);
        m.y = r ? im.y : (a ? mu.y : m.y);
        m.z = r ? im.z : (a ? mu.z : m.z);
        m.w = r ? im.w : (a ? mu.w : m.w);

        __builtin_nontemporal_store(m, (f32x4*)(mop + (size_t)t * CHW));

        if (do_cov) {
            f32x4 cu;
            cu.x = fminf(fmaxf(cc.x + cv.x, 0.f), 1.f);
            cu.y = fminf(fmaxf(cc.y + cv.y, 0.f), 1.f);
            cu.z = fminf(fmaxf(cc.z + cv.z, 0.f), 1.f);
            cu.w = fminf(fmaxf(cc.w + cv.w, 0.f), 1.f);
            cc.x = r ? cv.x : (a ? cu.x : cc.x);
            cc.y = r ? cv.y : (a ? cu.y : cc.y);
            cc.z = r ? cv.z : (a ? cu.z : cc.z);
            cc.w = r ? cv.w : (a ? cu.w : cc.w);
            __builtin_nontemporal_store(cc, (f32x4*)(cop + (size_t)t * HW));
        }
    }
}

extern "C" void kernel_launch(void* const* d_in, const int* in_sizes, int n_in,
                              void* d_out, int out_size, void* d_ws, size_t ws_size,
                              hipStream_t stream) {
    const float* img    = (const float*)d_in[0];
    const float* cov    = (const float*)d_in[1];
    const void*  addm   = d_in[2];
    const void*  resetm = d_in[3];
    float* out = (float*)d_out;

    li_fused_kernel<<<(CHW / 4) / 256, 256, 0, stream>>>(img, cov, addm, resetm, out);
}